// Round 1
// baseline (411.109 us; speedup 1.0000x reference)
//
#include <hip/hip_runtime.h>

// Problem constants (from the reference): B=32, T=12, H=448, W=304.
constexpr int B  = 32;
constexpr int T  = 12;
constexpr int H  = 448;
constexpr int W  = 304;
constexpr int BT = B * T;                 // 384
constexpr int HW = H * W;                 // 136192 (divisible by 4)
constexpr int HW4 = HW / 4;               // 34048 float4s per (b,t) plane
constexpr long long TOTAL = (long long)BT * HW;   // 52,297,728
constexpr int N4 = BT * HW4;              // 13,074,432 float4s total
constexpr float SCALE_FACTOR = 1.0f;

constexpr int NTHREADS = 256;
constexpr int NBLOCKS  = 2048;            // ~8 blocks/CU; grid-stride covers the rest

// Kernel 1: grid-stride partial reduction. Each block writes ONE partial sum
// to d_ws (no atomics -> deterministic, no need to pre-zero poisoned d_ws).
__global__ __launch_bounds__(NTHREADS)
void wmse_partial(const float4* __restrict__ pred,
                  const float4* __restrict__ targ,
                  const int*    __restrict__ target_months,   // [BT], 1-based
                  const float*  __restrict__ monthly_weights, // [12]
                  const float4* __restrict__ area_w4,         // [HW4]
                  float* __restrict__ partials)               // [NBLOCKS]
{
    // Hoist the per-(b,t) month-weight gather into LDS once per block.
    __shared__ float mw[BT];
    for (int i = threadIdx.x; i < BT; i += blockDim.x)
        mw[i] = monthly_weights[target_months[i] - 1];
    __syncthreads();

    float acc = 0.0f;
    for (int i = blockIdx.x * blockDim.x + threadIdx.x; i < N4;
         i += gridDim.x * blockDim.x) {
        int bt = i / HW4;               // magic-mul division, cheap vs HBM
        int sp = i - bt * HW4;          // spatial float4 index
        float4 p = pred[i];
        float4 t = targ[i];
        float4 a = area_w4[sp];         // L2-resident (545 KB)
        float  w = mw[bt];
        float d0 = (t.x - p.x) * w * a.x;
        float d1 = (t.y - p.y) * w * a.y;
        float d2 = (t.z - p.z) * w * a.z;
        float d3 = (t.w - p.w) * w * a.w;
        acc += d0 * d0 + d1 * d1 + d2 * d2 + d3 * d3;
    }

    // Wave-64 butterfly reduce, then cross-wave via LDS.
    #pragma unroll
    for (int off = 32; off > 0; off >>= 1)
        acc += __shfl_down(acc, off);

    __shared__ float wsum[NTHREADS / 64];
    const int lane = threadIdx.x & 63;
    const int wid  = threadIdx.x >> 6;
    if (lane == 0) wsum[wid] = acc;
    __syncthreads();
    if (threadIdx.x == 0) {
        float s = 0.0f;
        #pragma unroll
        for (int w2 = 0; w2 < NTHREADS / 64; ++w2) s += wsum[w2];
        partials[blockIdx.x] = s;
    }
}

// Kernel 2: one block folds the NBLOCKS partials and writes the mean.
__global__ __launch_bounds__(NTHREADS)
void wmse_final(const float* __restrict__ partials, float* __restrict__ out)
{
    float acc = 0.0f;
    for (int i = threadIdx.x; i < NBLOCKS; i += blockDim.x)
        acc += partials[i];

    #pragma unroll
    for (int off = 32; off > 0; off >>= 1)
        acc += __shfl_down(acc, off);

    __shared__ float wsum[NTHREADS / 64];
    const int lane = threadIdx.x & 63;
    const int wid  = threadIdx.x >> 6;
    if (lane == 0) wsum[wid] = acc;
    __syncthreads();
    if (threadIdx.x == 0) {
        float s = 0.0f;
        #pragma unroll
        for (int w2 = 0; w2 < NTHREADS / 64; ++w2) s += wsum[w2];
        out[0] = s * (SCALE_FACTOR / (float)TOTAL);
    }
}

extern "C" void kernel_launch(void* const* d_in, const int* in_sizes, int n_in,
                              void* d_out, int out_size, void* d_ws, size_t ws_size,
                              hipStream_t stream) {
    const float4* pred = (const float4*)d_in[0];
    const float4* targ = (const float4*)d_in[1];
    const int*    tm   = (const int*)d_in[2];
    const float*  mw   = (const float*)d_in[3];
    const float4* aw   = (const float4*)d_in[4];
    float* out = (float*)d_out;
    float* partials = (float*)d_ws;   // NBLOCKS * 4 bytes, rewritten every call

    wmse_partial<<<NBLOCKS, NTHREADS, 0, stream>>>(pred, targ, tm, mw, aw, partials);
    wmse_final<<<1, NTHREADS, 0, stream>>>(partials, out);
}